// Round 4
// baseline (185.598 us; speedup 1.0000x reference)
//
#include <hip/hip_runtime.h>

#define B_ 16
#define C_ 256
#define N_ 1024
#define NH 8
#define HD 32
#define KD 16
#define QKV_OUT_ 512
#define BN_EPS 1e-3f
// scale folded with 1/ln2 so softmax uses exp2 directly (v_exp_f32 native)
#define SCALE2_ (0.25f * 1.44269504088896f)

typedef __attribute__((ext_vector_type(8))) short short8;
typedef __attribute__((ext_vector_type(16))) float float16;

__device__ inline unsigned short f2bf(float f) {
  unsigned int u = __float_as_uint(f);
  return (unsigned short)((u + 0x7FFF + ((u >> 16) & 1)) >> 16);  // RNE
}
__device__ inline float bf2f(unsigned short s) {
  return __uint_as_float(((unsigned int)s) << 16);
}
__device__ inline float16 zero16() {
  float16 z;
  #pragma unroll
  for (int i = 0; i < 16; ++i) z[i] = 0.f;
  return z;
}
// pack two f32 into bf16x2 (truncate): low = a, high = b; one v_perm_b32
__device__ inline unsigned int pack_bf16_trunc(float a, float b) {
  return __builtin_amdgcn_perm(__float_as_uint(b), __float_as_uint(a), 0x07060302u);
}

// ---------------------------------------------------------------------------
// Fold BN into conv weights: W'[o][c] = W[o][c]*inv_o (bf16), bias_o.
// ---------------------------------------------------------------------------
__global__ __launch_bounds__(256) void fold_weights(
    const float* __restrict__ qkv_w, const float* __restrict__ qg,
    const float* __restrict__ qb, const float* __restrict__ qm,
    const float* __restrict__ qv,
    const float* __restrict__ proj_w, const float* __restrict__ pg,
    const float* __restrict__ pb, const float* __restrict__ pm,
    const float* __restrict__ pv,
    unsigned short* __restrict__ wq, float* __restrict__ biasq,
    unsigned short* __restrict__ wp, float* __restrict__ biasp)
{
  const int o = blockIdx.x, c = threadIdx.x;
  if (o < QKV_OUT_) {
    float inv = qg[o] * rsqrtf(qv[o] + BN_EPS);
    wq[o * C_ + c] = f2bf(qkv_w[o * C_ + c] * inv);
    if (c == 0) biasq[o] = qb[o] - qm[o] * inv;
  } else {
    int oo = o - QKV_OUT_;
    float inv = pg[oo] * rsqrtf(pv[oo] + BN_EPS);
    wp[oo * C_ + c] = f2bf(proj_w[oo * C_ + c] * inv);
    if (c == 0) biasp[oo] = pb[oo] - pm[oo] * inv;
  }
}

// ---------------------------------------------------------------------------
// MFMA GEMM + bias.  out[o][n] = sum_c W'[o][c] in[c][n] + bias[o].
// Block 256 thr = 4 waves; tile 64(O) x 256(N); wave (wm,wn) = 32o x 128n
// = 4 acc fragments sharing one A-fragment.  K staged 16 at a time into
// double-buffered LDS (rows of 20 shorts; b64 accesses, 2-way-free banks),
// ONE barrier per K-step, next chunk register-prefetched.
// MODE 0 (qkv): wm=0 waves write q+k transposed into qkT[b][h][token][32]
//               (q = cc 0..15, k = 16..31); wm=1 waves write v planar bf16
//               into vbuf[b][cv][n].
// MODE 1 (proj): fp32 planar out.
// ---------------------------------------------------------------------------
template <int MODE>
__global__ __launch_bounds__(256) void gemm_bn(
    const float* __restrict__ in, const unsigned short* __restrict__ wfold,
    const float* __restrict__ bias,
    unsigned short* __restrict__ qkT, unsigned short* __restrict__ vbuf,
    float* __restrict__ outf)
{
  __shared__ __align__(16) unsigned short xb[2][256][20];
  const int tid = threadIdx.x;
  const int wave = tid >> 6, lane = tid & 63, l31 = lane & 31, lh = lane >> 5;
  const int wm = wave & 1, wn = wave >> 1;
  const int nt = blockIdx.x, ot = blockIdx.y, b = blockIdx.z;

  const float* inb = in + (size_t)b * C_ * N_ + nt * 256 + tid;
  const unsigned short* wrow = wfold + (size_t)(ot * 64 + wm * 32 + l31) * C_;

  float16 acc[4];
  #pragma unroll
  for (int i = 0; i < 4; ++i) acc[i] = zero16();

  // prologue: stage K-step 0
  {
    unsigned int pk[8];
    #pragma unroll
    for (int q = 0; q < 8; ++q) {
      float a = inb[(size_t)(2 * q) * N_];
      float c = inb[(size_t)(2 * q + 1) * N_];
      pk[q] = pack_bf16_trunc(a, c);
    }
    #pragma unroll
    for (int q = 0; q < 4; ++q)
      *(uint2*)&xb[0][tid][q * 4] = make_uint2(pk[2 * q], pk[2 * q + 1]);
  }
  __syncthreads();

  for (int s = 0; s < 16; ++s) {
    const int buf = s & 1;
    float nxt[16];
    if (s < 15) {
      #pragma unroll
      for (int j = 0; j < 16; ++j)
        nxt[j] = inb[(size_t)((s + 1) * 16 + j) * N_];
    }

    short8 a8 = *(const short8*)(wrow + s * 16 + lh * 8);
    #pragma unroll
    for (int sub = 0; sub < 4; ++sub) {
      union { uint2 u[2]; short8 v; } bf;
      const unsigned short* p = &xb[buf][wn * 128 + sub * 32 + l31][lh * 8];
      bf.u[0] = *(const uint2*)p;
      bf.u[1] = *(const uint2*)(p + 4);
      acc[sub] = __builtin_amdgcn_mfma_f32_32x32x16_bf16(a8, bf.v, acc[sub], 0, 0, 0);
    }

    if (s < 15) {
      unsigned int pk[8];
      #pragma unroll
      for (int q = 0; q < 8; ++q)
        pk[q] = pack_bf16_trunc(nxt[2 * q], nxt[2 * q + 1]);
      #pragma unroll
      for (int q = 0; q < 4; ++q)
        *(uint2*)&xb[buf ^ 1][tid][q * 4] = make_uint2(pk[2 * q], pk[2 * q + 1]);
      __syncthreads();
    }
  }

  // ---- epilogue
  if constexpr (MODE == 0) {
    if (wm == 0) {
      // q+k -> token-major qkT[b][h=ot][token][cc 0..31]
      #pragma unroll
      for (int sub = 0; sub < 4; ++sub) {
        int token = nt * 256 + wn * 128 + sub * 32 + l31;
        unsigned short* row = qkT + (((size_t)b * NH + ot) * N_ + token) * 32;
        #pragma unroll
        for (int qd = 0; qd < 4; ++qd) {
          int cc0 = 8 * qd + 4 * lh;
          ushort4 r;
          r.x = f2bf(acc[sub][4 * qd + 0] + bias[ot * 64 + cc0 + 0]);
          r.y = f2bf(acc[sub][4 * qd + 1] + bias[ot * 64 + cc0 + 1]);
          r.z = f2bf(acc[sub][4 * qd + 2] + bias[ot * 64 + cc0 + 2]);
          r.w = f2bf(acc[sub][4 * qd + 3] + bias[ot * 64 + cc0 + 3]);
          *(ushort4*)(row + cc0) = r;
        }
      }
    } else {
      // v -> planar vbuf[b][cv = ot*32+cc][n] bf16
      #pragma unroll
      for (int r = 0; r < 16; ++r) {
        int cc = (r & 3) + 8 * (r >> 2) + 4 * lh;
        float bo = bias[ot * 64 + 32 + cc];
        unsigned short* vrow = vbuf + ((size_t)b * C_ + ot * 32 + cc) * N_ + nt * 256 + wn * 128 + l31;
        #pragma unroll
        for (int sub = 0; sub < 4; ++sub)
          vrow[sub * 32] = f2bf(acc[sub][r] + bo);
      }
    }
  } else {
    #pragma unroll
    for (int r = 0; r < 16; ++r) {
      int o = ot * 64 + wm * 32 + (r & 3) + 8 * (r >> 2) + 4 * lh;
      float bo = bias[o];
      float* orow = outf + ((size_t)b * C_ + o) * N_ + nt * 256 + wn * 128 + l31;
      #pragma unroll
      for (int sub = 0; sub < 4; ++sub)
        orow[sub * 32] = acc[sub][r] + bo;
    }
  }
}

// ---------------------------------------------------------------------------
// Barrier-free MFMA attention, token-major Q/K.  One wave = 32 queries.
// S^T = K (Q*scale') via mfma(A=K, B=Q); P = exp2(S^T) assembled in-register
// for the PV B-operand via perm-pack + shfl_xor(32).  No LDS, no barriers.
// ---------------------------------------------------------------------------
__global__ __launch_bounds__(256) void attn_mfma(
    const unsigned short* __restrict__ qkT, const unsigned short* __restrict__ vbuf,
    float* __restrict__ vattn)
{
  const int wave = threadIdx.x >> 6, lane = threadIdx.x & 63;
  const int l31 = lane & 31, lh = lane >> 5;
  const int h = blockIdx.y, b = blockIdx.z;
  const int qbase = blockIdx.x * 128 + wave * 32;

  const unsigned short* qkb = qkT + ((size_t)b * NH + h) * N_ * 32;
  const unsigned short* vp = vbuf + ((size_t)b * C_ + h * HD + l31) * N_;

  // Q fragment (B of S^T): B[k=d][n=query=l31]; 16B row load + fold scale
  short8 qf;
  {
    const unsigned short* qr = qkb + (size_t)(qbase + l31) * 32 + lh * 8;
    #pragma unroll
    for (int j = 0; j < 8; ++j)
      qf[j] = (short)f2bf(bf2f(qr[j]) * SCALE2_);
  }

  float16 oacc = zero16();
  float lsum = 0.f;

  for (int kc = 0; kc < N_; kc += 128) {
    #pragma unroll
    for (int t = 0; t < 4; ++t) {
      int key0 = kc + t * 32;
      // K fragment (A): A[m=key=l31][k=d] -- one 16B row load
      short8 kf = *(const short8*)(qkb + (size_t)(key0 + l31) * 32 + 16 + lh * 8);
      float16 st = __builtin_amdgcn_mfma_f32_32x32x16_bf16(kf, qf, zero16(), 0, 0, 0);

      // P = exp2(S); pack adjacent-key pairs (trunc bf16)
      unsigned int u[8];
      #pragma unroll
      for (int q = 0; q < 8; ++q) {
        float pe = exp2f(st[2 * q]);
        float po = exp2f(st[2 * q + 1]);
        lsum += pe + po;
        u[q] = pack_bf16_trunc(pe, po);
      }
      unsigned int e[8];
      #pragma unroll
      for (int q = 0; q < 8; ++q)
        e[q] = (unsigned int)__shfl_xor((int)u[q], 32, 64);

      #pragma unroll
      for (int f = 0; f < 2; ++f) {
        union { unsigned int w[4]; short8 s; } bf;
        int q0 = f * 4;
        bf.w[0] = lh ? e[q0 + 2] : u[q0 + 0];
        bf.w[1] = lh ? e[q0 + 3] : u[q0 + 1];
        bf.w[2] = lh ? u[q0 + 2] : e[q0 + 0];
        bf.w[3] = lh ? u[q0 + 3] : e[q0 + 1];
        // V fragment (A): A[m=d=l31][k=key], contiguous 16B
        short8 vf = *(const short8*)(vp + key0 + f * 16 + lh * 8);
        oacc = __builtin_amdgcn_mfma_f32_32x32x16_bf16(vf, bf.s, oacc, 0, 0, 0);
      }
    }
  }

  lsum += __shfl_xor(lsum, 32, 64);
  float linv = 1.f / lsum;

  #pragma unroll
  for (int r = 0; r < 16; ++r) {
    int d = (r & 3) + 8 * (r >> 2) + 4 * lh;
    vattn[((size_t)b * C_ + h * HD + d) * N_ + qbase + l31] = oacc[r] * linv;
  }
}

// ---------------------------------------------------------------------------
// depthwise 3x3 + BN on v (bf16 planar vbuf), added in-place into vattn(f32).
// ---------------------------------------------------------------------------
__global__ __launch_bounds__(256) void dwconv_bn_add(
    const unsigned short* __restrict__ vbuf, const float* __restrict__ pw,
    const float* __restrict__ gamma, const float* __restrict__ beta,
    const float* __restrict__ mean, const float* __restrict__ var,
    float* __restrict__ vsum)
{
  __shared__ float t[34][34];
  const int c = blockIdx.x, b = blockIdx.y;
  const int tid = threadIdx.x;
  const unsigned short* vp = vbuf + ((size_t)b * C_ + c) * N_;

  #pragma unroll
  for (int r = 0; r < 4; ++r) {
    int idx = r * 256 + tid;
    t[(idx >> 5) + 1][(idx & 31) + 1] = bf2f(vp[idx]);
  }
  if (tid < 34) {
    t[0][tid] = 0.f; t[33][tid] = 0.f;
    t[tid][0] = 0.f; t[tid][33] = 0.f;
  }
  __syncthreads();

  float w9[9];
  #pragma unroll
  for (int i = 0; i < 9; ++i) w9[i] = pw[c * 9 + i];
  float inv = gamma[c] * rsqrtf(var[c] + BN_EPS);
  float add = beta[c] - mean[c] * inv;

  float* op = vsum + ((size_t)b * C_ + c) * N_;
  #pragma unroll
  for (int r = 0; r < 4; ++r) {
    int idx = r * 256 + tid;
    int y = idx >> 5, x = idx & 31;
    float s = 0.f;
    #pragma unroll
    for (int dy = 0; dy < 3; ++dy)
      #pragma unroll
      for (int dx = 0; dx < 3; ++dx)
        s += t[y + dy][x + dx] * w9[dy * 3 + dx];
    op[idx] = s * inv + add + op[idx];
  }
}

// ---------------------------------------------------------------------------
extern "C" void kernel_launch(void* const* d_in, const int* in_sizes, int n_in,
                              void* d_out, int out_size, void* d_ws, size_t ws_size,
                              hipStream_t stream) {
  const float* x          = (const float*)d_in[0];
  const float* qkv_w      = (const float*)d_in[1];
  const float* qkv_gamma  = (const float*)d_in[2];
  const float* qkv_beta   = (const float*)d_in[3];
  const float* qkv_mean   = (const float*)d_in[4];
  const float* qkv_var    = (const float*)d_in[5];
  const float* pe_w       = (const float*)d_in[6];
  const float* pe_gamma   = (const float*)d_in[7];
  const float* pe_beta    = (const float*)d_in[8];
  const float* pe_mean    = (const float*)d_in[9];
  const float* pe_var     = (const float*)d_in[10];
  const float* proj_w     = (const float*)d_in[11];
  const float* proj_gamma = (const float*)d_in[12];
  const float* proj_beta  = (const float*)d_in[13];
  const float* proj_mean  = (const float*)d_in[14];
  const float* proj_var   = (const float*)d_in[15];
  float* out = (float*)d_out;

  char* ws = (char*)d_ws;
  unsigned short* qkT = (unsigned short*)ws;                      // 8 MB
  ws += (size_t)B_ * NH * N_ * 32 * sizeof(unsigned short);
  unsigned short* vbuf = (unsigned short*)ws;                     // 8 MB
  ws += (size_t)B_ * C_ * N_ * sizeof(unsigned short);
  float* vattn = (float*)ws;                                      // 16 MB
  ws += (size_t)B_ * C_ * N_ * sizeof(float);
  unsigned short* wq = (unsigned short*)ws;                       // 256 KB
  ws += (size_t)QKV_OUT_ * C_ * sizeof(unsigned short);
  unsigned short* wp = (unsigned short*)ws;                       // 128 KB
  ws += (size_t)C_ * C_ * sizeof(unsigned short);
  float* biasq = (float*)ws; ws += QKV_OUT_ * sizeof(float);
  float* biasp = (float*)ws;

  // 0) fold BN into weights (bf16) + biases
  fold_weights<<<dim3(QKV_OUT_ + C_), 256, 0, stream>>>(
      qkv_w, qkv_gamma, qkv_beta, qkv_mean, qkv_var,
      proj_w, proj_gamma, proj_beta, proj_mean, proj_var,
      wq, biasq, wp, biasp);

  // 1) qkv GEMM -> qkT (token-major q,k) + vbuf (planar v)
  gemm_bn<0><<<dim3(4, 8, 16), 256, 0, stream>>>(
      x, wq, biasq, qkT, vbuf, nullptr);

  // 2) attention (MFMA, barrier-free)
  attn_mfma<<<dim3(8, NH, B_), 256, 0, stream>>>(qkT, vbuf, vattn);

  // 3) vattn += BN(dwconv3x3(v))
  dwconv_bn_add<<<dim3(C_, B_), 256, 0, stream>>>(
      vbuf, pe_w, pe_gamma, pe_beta, pe_mean, pe_var, vattn);

  // 4) out = proj GEMM (fp32)
  gemm_bn<1><<<dim3(4, 4, 16), 256, 0, stream>>>(
      vattn, wp, biasp, nullptr, nullptr, out);
}